// Round 2
// baseline (4140.496 us; speedup 1.0000x reference)
//
#include <hip/hip_runtime.h>

#define DIM 128
#define TILE_ROWS 32

// WT[l][k][c] = W[l][c][k]  (so GEMM reads are coalesced & LDS conflict-free)
__global__ __launch_bounds__(128) void transpose_w_kernel(
    const float* __restrict__ W, float* __restrict__ WT)
{
    const int b = blockIdx.x;          // layer*128 + k
    const int layer = b >> 7;
    const int k = b & 127;
    const int c = threadIdx.x;
    WT[((size_t)layer << 14) + (k << 7) + c] = W[((size_t)layer << 14) + (c << 7) + k];
}

__global__ __launch_bounds__(256) void zero_kernel(float4* __restrict__ p, int n4)
{
    const int i = blockIdx.x * 256 + threadIdx.x;
    if (i < n4) p[i] = make_float4(0.f, 0.f, 0.f, 0.f);
}

// h[r][c] = sum_k x[r][k] * W[c][k] + bias[c]
// apply_relu=0: x = concat(xa rows [0,nrows_a), xb rows [nrows_a,N)), no relu
// apply_relu=1: x = relu(xa)
__global__ __launch_bounds__(256) void gemm_relu_kernel(
    const float* __restrict__ xa, const float* __restrict__ xb,
    const float* __restrict__ WT, const float* __restrict__ bias,
    float* __restrict__ h, int apply_relu, int nrows_a, int N)
{
    __shared__ float WTs[DIM * DIM];       // WTs[k*128+c]
    __shared__ float Xs[TILE_ROWS * DIM];  // Xs[r*128+k]
    const int tid = threadIdx.x;

    for (int i = tid; i < DIM * DIM / 4; i += 256)
        ((float4*)WTs)[i] = ((const float4*)WT)[i];

    const int rbase = blockIdx.x * TILE_ROWS;
    for (int i = tid; i < TILE_ROWS * DIM / 4; i += 256) {
        int r = i >> 5;
        int grow = rbase + r;
        if (grow >= N) grow = N - 1;
        float4 v;
        if (apply_relu) {
            v = ((const float4*)(xa + (size_t)grow * DIM))[i & 31];
            v.x = fmaxf(v.x, 0.f); v.y = fmaxf(v.y, 0.f);
            v.z = fmaxf(v.z, 0.f); v.w = fmaxf(v.w, 0.f);
        } else {
            const float* sp = (grow < nrows_a) ? xa + (size_t)grow * DIM
                                               : xb + (size_t)(grow - nrows_a) * DIM;
            v = ((const float4*)sp)[i & 31];
        }
        ((float4*)Xs)[i] = v;
    }
    __syncthreads();

    const int c0 = (tid & 31) * 4;   // 4 consecutive output cols
    const int rset = tid >> 5;       // 8 row-groups
    const float4 bv = ((const float4*)bias)[tid & 31];
    float4 acc[4] = {bv, bv, bv, bv};

    for (int k = 0; k < DIM; k += 4) {
        const float4 w0 = *(const float4*)&WTs[(k + 0) * DIM + c0];
        const float4 w1 = *(const float4*)&WTs[(k + 1) * DIM + c0];
        const float4 w2 = *(const float4*)&WTs[(k + 2) * DIM + c0];
        const float4 w3 = *(const float4*)&WTs[(k + 3) * DIM + c0];
        #pragma unroll
        for (int m = 0; m < 4; ++m) {
            const float4 xv = *(const float4*)&Xs[(rset + 8 * m) * DIM + k];
            acc[m].x = fmaf(xv.w, w3.x, fmaf(xv.z, w2.x, fmaf(xv.y, w1.x, fmaf(xv.x, w0.x, acc[m].x))));
            acc[m].y = fmaf(xv.w, w3.y, fmaf(xv.z, w2.y, fmaf(xv.y, w1.y, fmaf(xv.x, w0.y, acc[m].y))));
            acc[m].z = fmaf(xv.w, w3.z, fmaf(xv.z, w2.z, fmaf(xv.y, w1.z, fmaf(xv.x, w0.z, acc[m].z))));
            acc[m].w = fmaf(xv.w, w3.w, fmaf(xv.z, w2.w, fmaf(xv.y, w1.w, fmaf(xv.x, w0.w, acc[m].w))));
        }
    }
    #pragma unroll
    for (int m = 0; m < 4; ++m) {
        int grow = rbase + rset + 8 * m;
        if (grow < N)
            ((float4*)(h + (size_t)grow * DIM))[tid & 31] = acc[m];
    }
}

// One wave per edge: 64 lanes x float2 = 512B coalesced gather, 128 fp32 atomics
__global__ __launch_bounds__(256) void edge_scatter_kernel(
    const int* __restrict__ ei, const float* __restrict__ ew,
    const float* __restrict__ h, float* __restrict__ agg, int E)
{
    const int e = blockIdx.x * 4 + (threadIdx.x >> 6);
    if (e >= E) return;
    const int lane = threadIdx.x & 63;
    const int src = ei[e];
    const int dst = ei[E + e];
    const float w = ew[e];
    const float2 v = ((const float2*)(h + (size_t)src * DIM))[lane];
    float* ap = agg + (size_t)dst * DIM + lane * 2;
    unsafeAtomicAdd(ap, w * v.x);
    unsafeAtomicAdd(ap + 1, w * v.y);
}

__global__ __launch_bounds__(256) void relu_kernel(float4* __restrict__ p, int n4)
{
    const int i = blockIdx.x * 256 + threadIdx.x;
    if (i < n4) {
        float4 v = p[i];
        v.x = fmaxf(v.x, 0.f); v.y = fmaxf(v.y, 0.f);
        v.z = fmaxf(v.z, 0.f); v.w = fmaxf(v.w, 0.f);
        p[i] = v;
    }
}

extern "C" void kernel_launch(void* const* d_in, const int* in_sizes, int n_in,
                              void* d_out, int out_size, void* d_ws, size_t ws_size,
                              hipStream_t stream)
{
    const int*   ei        = (const int*)d_in[0];    // [2][E]
    const float* ew        = (const float*)d_in[1];  // [E]
    const float* row_embed = (const float*)d_in[2];  // [nrows][128]
    const float* col_embed = (const float*)d_in[3];  // [ncols][128]
    const float* W         = (const float*)d_in[4];  // [L][128][128]
    const float* bias      = (const float*)d_in[5];  // [L][128]

    const int E     = in_sizes[1];
    const int nrows = in_sizes[2] / DIM;
    const int ncols = in_sizes[3] / DIM;
    const int N     = nrows + ncols;
    const int L     = in_sizes[5] / DIM;

    float* agg = (float*)d_out;                 // [N][128] — doubles as layer input
    float* WT  = (float*)d_ws;                  // [L][128][128]
    float* h   = WT + (size_t)L * DIM * DIM;    // [N][128]

    transpose_w_kernel<<<L * DIM, DIM, 0, stream>>>(W, WT);

    const int gemm_blocks = (N + TILE_ROWS - 1) / TILE_ROWS;
    const int edge_blocks = (E + 3) / 4;
    const int n4 = N * DIM / 4;
    const int zero_blocks = (n4 + 255) / 256;

    for (int l = 0; l < L; ++l) {
        if (l == 0)
            gemm_relu_kernel<<<gemm_blocks, 256, 0, stream>>>(
                row_embed, col_embed, WT, bias, h, 0, nrows, N);
        else
            gemm_relu_kernel<<<gemm_blocks, 256, 0, stream>>>(
                agg, nullptr, WT + (size_t)l * DIM * DIM, bias + (size_t)l * DIM,
                h, 1, nrows, N);
        zero_kernel<<<zero_blocks, 256, 0, stream>>>((float4*)agg, n4);
        edge_scatter_kernel<<<edge_blocks, 256, 0, stream>>>(ei, ew, h, agg, E);
    }
    relu_kernel<<<zero_blocks, 256, 0, stream>>>((float4*)agg, n4);
}

// Round 3
// 749.576 us; speedup vs baseline: 5.5238x; 5.5238x over previous
//
#include <hip/hip_runtime.h>

#define DIM 128
#define TILE_ROWS 32

// ---------------- weight transpose ----------------
// WT[l][k][c] = W[l][c][k]
__global__ __launch_bounds__(128) void transpose_w_kernel(
    const float* __restrict__ W, float* __restrict__ WT)
{
    const int b = blockIdx.x;          // layer*128 + k
    const int layer = b >> 7;
    const int k = b & 127;
    const int c = threadIdx.x;
    WT[((size_t)layer << 14) + (k << 7) + c] = W[((size_t)layer << 14) + (c << 7) + k];
}

// ---------------- generic zero ----------------
__global__ __launch_bounds__(256) void zero_f4_kernel(float4* __restrict__ p, int n4)
{
    const int i = blockIdx.x * 256 + threadIdx.x;
    if (i < n4) p[i] = make_float4(0.f, 0.f, 0.f, 0.f);
}

__global__ __launch_bounds__(256) void zero_i_kernel(int* __restrict__ p, int n)
{
    const int i = blockIdx.x * 256 + threadIdx.x;
    if (i < n) p[i] = 0;
}

// ---------------- CSR build ----------------
__global__ __launch_bounds__(256) void hist_kernel(
    const int* __restrict__ ei, int* __restrict__ counts, int E)
{
    const int e = blockIdx.x * 256 + threadIdx.x;
    if (e < E) atomicAdd(&counts[ei[E + e]], 1);
}

// per-chunk (1024 counts) sums
__global__ __launch_bounds__(256) void partial_sum_kernel(
    const int* __restrict__ counts, int* __restrict__ partial, int N)
{
    __shared__ int tsum[256];
    const int tid = threadIdx.x;
    const int base = blockIdx.x * 1024 + tid * 4;
    int s = 0;
    if (base + 3 < N) {
        int4 v = *(const int4*)&counts[base];
        s = v.x + v.y + v.z + v.w;
    } else {
        for (int j = 0; j < 4; ++j) if (base + j < N) s += counts[base + j];
    }
    tsum[tid] = s;
    __syncthreads();
    for (int off = 128; off; off >>= 1) {
        if (tid < off) tsum[tid] += tsum[tid + off];
        __syncthreads();
    }
    if (tid == 0) partial[blockIdx.x] = tsum[0];
}

// exclusive scan of chunk sums (single thread — ~100 entries)
__global__ void scan_partials_kernel(int* __restrict__ partial, int nchunks)
{
    if (threadIdx.x == 0 && blockIdx.x == 0) {
        int run = 0;
        for (int i = 0; i < nchunks; ++i) {
            int t = partial[i];
            partial[i] = run;
            run += t;
        }
    }
}

// exclusive scan within chunk + chunk offset -> row_ptr; counts becomes cursor
__global__ __launch_bounds__(256) void scan_chunk_kernel(
    int* __restrict__ counts, int* __restrict__ row_ptr,
    const int* __restrict__ partial, int N, int E)
{
    __shared__ int tsum[256];
    const int tid = threadIdx.x;
    const int base = blockIdx.x * 1024 + tid * 4;
    int c0 = 0, c1 = 0, c2 = 0, c3 = 0;
    if (base + 3 < N) {
        int4 v = *(const int4*)&counts[base];
        c0 = v.x; c1 = v.y; c2 = v.z; c3 = v.w;
    } else {
        if (base + 0 < N) c0 = counts[base + 0];
        if (base + 1 < N) c1 = counts[base + 1];
        if (base + 2 < N) c2 = counts[base + 2];
        if (base + 3 < N) c3 = counts[base + 3];
    }
    const int s = c0 + c1 + c2 + c3;
    tsum[tid] = s;
    __syncthreads();
    // Hillis-Steele inclusive scan
    int x = s;
    for (int off = 1; off < 256; off <<= 1) {
        int y = (tid >= off) ? tsum[tid - off] : 0;
        __syncthreads();
        x += (tid >= off) ? y : 0;
        tsum[tid] = x;
        __syncthreads();
    }
    int o = partial[blockIdx.x] + x - s;   // exclusive prefix for this thread
    if (base + 0 < N) { row_ptr[base + 0] = o;      counts[base + 0] = o;      }
    if (base + 1 < N) { row_ptr[base + 1] = o + c0; counts[base + 1] = o + c0; }
    if (base + 2 < N) { row_ptr[base + 2] = o + c0 + c1; counts[base + 2] = o + c0 + c1; }
    if (base + 3 < N) { row_ptr[base + 3] = o + c0 + c1 + c2; counts[base + 3] = o + c0 + c1 + c2; }
    if (tid == 0 && blockIdx.x == 0) row_ptr[N] = E;
}

__global__ __launch_bounds__(256) void csr_scatter_kernel(
    const int* __restrict__ ei, const float* __restrict__ ew,
    int* __restrict__ cursor, int2* __restrict__ rec, int E)
{
    const int e = blockIdx.x * 256 + threadIdx.x;
    if (e < E) {
        const int dst = ei[E + e];
        const int pos = atomicAdd(&cursor[dst], 1);
        rec[pos] = make_int2(ei[e], __float_as_int(ew[e]));
    }
}

// ---------------- dense GEMM: h[r][c] = sum_k x[r][k] * W[c][k] + bias[c] ----------------
// apply_relu=1: relu xa rows on load (fallback path only)
__global__ __launch_bounds__(256) void gemm_relu_kernel(
    const float* __restrict__ xa, const float* __restrict__ xb,
    const float* __restrict__ WT, const float* __restrict__ bias,
    float* __restrict__ h, int apply_relu, int nrows_a, int N)
{
    __shared__ float WTs[DIM * DIM];       // WTs[k*128+c]
    __shared__ float Xs[TILE_ROWS * DIM];  // Xs[r*128+k]
    const int tid = threadIdx.x;

    for (int i = tid; i < DIM * DIM / 4; i += 256)
        ((float4*)WTs)[i] = ((const float4*)WT)[i];

    const int rbase = blockIdx.x * TILE_ROWS;
    for (int i = tid; i < TILE_ROWS * DIM / 4; i += 256) {
        int r = i >> 5;
        int grow = rbase + r;
        if (grow >= N) grow = N - 1;
        const float* sp = (grow < nrows_a) ? xa + (size_t)grow * DIM
                                           : xb + (size_t)(grow - nrows_a) * DIM;
        float4 v = ((const float4*)sp)[i & 31];
        if (apply_relu) {
            v.x = fmaxf(v.x, 0.f); v.y = fmaxf(v.y, 0.f);
            v.z = fmaxf(v.z, 0.f); v.w = fmaxf(v.w, 0.f);
        }
        ((float4*)Xs)[i] = v;
    }
    __syncthreads();

    const int c0 = (tid & 31) * 4;
    const int rset = tid >> 5;
    const float4 bv = ((const float4*)bias)[tid & 31];
    float4 acc[4] = {bv, bv, bv, bv};

    for (int k = 0; k < DIM; k += 4) {
        const float4 w0 = *(const float4*)&WTs[(k + 0) * DIM + c0];
        const float4 w1 = *(const float4*)&WTs[(k + 1) * DIM + c0];
        const float4 w2 = *(const float4*)&WTs[(k + 2) * DIM + c0];
        const float4 w3 = *(const float4*)&WTs[(k + 3) * DIM + c0];
        #pragma unroll
        for (int m = 0; m < 4; ++m) {
            const float4 xv = *(const float4*)&Xs[(rset + 8 * m) * DIM + k];
            acc[m].x = fmaf(xv.w, w3.x, fmaf(xv.z, w2.x, fmaf(xv.y, w1.x, fmaf(xv.x, w0.x, acc[m].x))));
            acc[m].y = fmaf(xv.w, w3.y, fmaf(xv.z, w2.y, fmaf(xv.y, w1.y, fmaf(xv.x, w0.y, acc[m].y))));
            acc[m].z = fmaf(xv.w, w3.z, fmaf(xv.z, w2.z, fmaf(xv.y, w1.z, fmaf(xv.x, w0.z, acc[m].z))));
            acc[m].w = fmaf(xv.w, w3.w, fmaf(xv.z, w2.w, fmaf(xv.y, w1.w, fmaf(xv.x, w0.w, acc[m].w))));
        }
    }
    #pragma unroll
    for (int m = 0; m < 4; ++m) {
        int grow = rbase + rset + 8 * m;
        if (grow < N)
            ((float4*)(h + (size_t)grow * DIM))[tid & 31] = acc[m];
    }
}

// ---------------- CSR aggregate + ReLU: one wave per dst row ----------------
__global__ __launch_bounds__(256) void csr_agg_relu_kernel(
    const int* __restrict__ row_ptr, const int2* __restrict__ rec,
    const float* __restrict__ h, float* __restrict__ out, int N)
{
    const int dst = blockIdx.x * 4 + (threadIdx.x >> 6);
    if (dst >= N) return;
    const int lane = threadIdx.x & 63;
    const int beg = row_ptr[dst];
    const int end = row_ptr[dst + 1];
    float2 acc = make_float2(0.f, 0.f);
    int p = beg;
    for (; p + 1 < end; p += 2) {
        const int2 r0 = rec[p];
        const int2 r1 = rec[p + 1];
        const float w0 = __int_as_float(r0.y);
        const float w1 = __int_as_float(r1.y);
        const float2 v0 = ((const float2*)(h + (size_t)r0.x * DIM))[lane];
        const float2 v1 = ((const float2*)(h + (size_t)r1.x * DIM))[lane];
        acc.x = fmaf(w0, v0.x, acc.x);
        acc.y = fmaf(w0, v0.y, acc.y);
        acc.x = fmaf(w1, v1.x, acc.x);
        acc.y = fmaf(w1, v1.y, acc.y);
    }
    if (p < end) {
        const int2 r0 = rec[p];
        const float w0 = __int_as_float(r0.y);
        const float2 v0 = ((const float2*)(h + (size_t)r0.x * DIM))[lane];
        acc.x = fmaf(w0, v0.x, acc.x);
        acc.y = fmaf(w0, v0.y, acc.y);
    }
    acc.x = fmaxf(acc.x, 0.f);
    acc.y = fmaxf(acc.y, 0.f);
    ((float2*)(out + (size_t)dst * DIM))[lane] = acc;
}

// ---------------- fallback atomic scatter (R1 path) ----------------
__global__ __launch_bounds__(256) void edge_scatter_kernel(
    const int* __restrict__ ei, const float* __restrict__ ew,
    const float* __restrict__ h, float* __restrict__ agg, int E)
{
    const int e = blockIdx.x * 4 + (threadIdx.x >> 6);
    if (e >= E) return;
    const int lane = threadIdx.x & 63;
    const int src = ei[e];
    const int dst = ei[E + e];
    const float w = ew[e];
    const float2 v = ((const float2*)(h + (size_t)src * DIM))[lane];
    float* ap = agg + (size_t)dst * DIM + lane * 2;
    unsafeAtomicAdd(ap, w * v.x);
    unsafeAtomicAdd(ap + 1, w * v.y);
}

__global__ __launch_bounds__(256) void relu_kernel(float4* __restrict__ p, int n4)
{
    const int i = blockIdx.x * 256 + threadIdx.x;
    if (i < n4) {
        float4 v = p[i];
        v.x = fmaxf(v.x, 0.f); v.y = fmaxf(v.y, 0.f);
        v.z = fmaxf(v.z, 0.f); v.w = fmaxf(v.w, 0.f);
        p[i] = v;
    }
}

extern "C" void kernel_launch(void* const* d_in, const int* in_sizes, int n_in,
                              void* d_out, int out_size, void* d_ws, size_t ws_size,
                              hipStream_t stream)
{
    const int*   ei        = (const int*)d_in[0];    // [2][E]
    const float* ew        = (const float*)d_in[1];  // [E]
    const float* row_embed = (const float*)d_in[2];  // [nrows][128]
    const float* col_embed = (const float*)d_in[3];  // [ncols][128]
    const float* W         = (const float*)d_in[4];  // [L][128][128]
    const float* bias      = (const float*)d_in[5];  // [L][128]

    const int E     = in_sizes[1];
    const int nrows = in_sizes[2] / DIM;
    const int ncols = in_sizes[3] / DIM;
    const int N     = nrows + ncols;
    const int L     = in_sizes[5] / DIM;

    // workspace layout (16B aligned slabs)
    size_t off = 0;
    auto alloc = [&](size_t bytes) -> char* {
        char* p = (char*)d_ws + off;
        off = (off + bytes + 15) & ~(size_t)15;
        return p;
    };
    float* WT      = (float*)alloc((size_t)L * DIM * DIM * sizeof(float));
    float* h       = (float*)alloc((size_t)N * DIM * sizeof(float));
    int*   row_ptr = (int*)  alloc((size_t)(N + 1) * sizeof(int));
    int*   counts  = (int*)  alloc((size_t)N * sizeof(int));       // becomes cursor
    int*   partial = (int*)  alloc(1024 * sizeof(int));
    int2*  rec     = (int2*) alloc((size_t)E * sizeof(int2));
    const size_t needed = off;

    transpose_w_kernel<<<L * DIM, DIM, 0, stream>>>(W, WT);

    const int gemm_blocks = (N + TILE_ROWS - 1) / TILE_ROWS;
    const int n4 = N * DIM / 4;
    const int zero_blocks = (n4 + 255) / 256;
    const int edge_blocks256 = (E + 255) / 256;
    float* agg = (float*)d_out;

    if (ws_size >= needed) {
        // ---- CSR path ----
        const int nchunks = (N + 1023) / 1024;
        zero_i_kernel<<<(N + 255) / 256, 256, 0, stream>>>(counts, N);
        hist_kernel<<<edge_blocks256, 256, 0, stream>>>(ei, counts, E);
        partial_sum_kernel<<<nchunks, 256, 0, stream>>>(counts, partial, N);
        scan_partials_kernel<<<1, 64, 0, stream>>>(partial, nchunks);
        scan_chunk_kernel<<<nchunks, 256, 0, stream>>>(counts, row_ptr, partial, N, E);
        csr_scatter_kernel<<<edge_blocks256, 256, 0, stream>>>(ei, ew, counts, rec, E);

        const int agg_blocks = (N + 3) / 4;
        for (int l = 0; l < L; ++l) {
            if (l == 0)
                gemm_relu_kernel<<<gemm_blocks, 256, 0, stream>>>(
                    row_embed, col_embed, WT, bias, h, 0, nrows, N);
            else
                gemm_relu_kernel<<<gemm_blocks, 256, 0, stream>>>(
                    agg, agg, WT + (size_t)l * DIM * DIM, bias + (size_t)l * DIM,
                    h, 0, N, N);
            csr_agg_relu_kernel<<<agg_blocks, 256, 0, stream>>>(row_ptr, rec, h, agg, N);
        }
    } else {
        // ---- fallback: R1 atomic path (needs only WT + h) ----
        const int edge_blocks = (E + 3) / 4;
        for (int l = 0; l < L; ++l) {
            if (l == 0)
                gemm_relu_kernel<<<gemm_blocks, 256, 0, stream>>>(
                    row_embed, col_embed, WT, bias, h, 0, nrows, N);
            else
                gemm_relu_kernel<<<gemm_blocks, 256, 0, stream>>>(
                    agg, agg, WT + (size_t)l * DIM * DIM, bias + (size_t)l * DIM,
                    h, 1, N, N);
            zero_f4_kernel<<<zero_blocks, 256, 0, stream>>>((float4*)agg, n4);
            edge_scatter_kernel<<<edge_blocks, 256, 0, stream>>>(ei, ew, h, agg, E);
        }
        relu_kernel<<<zero_blocks, 256, 0, stream>>>((float4*)agg, n4);
    }
}

// Round 4
// 623.310 us; speedup vs baseline: 6.6428x; 1.2026x over previous
//
#include <hip/hip_runtime.h>
#include <hip/hip_fp16.h>

#define DIM 128
#define TILE_ROWS 32

// ---------------- weight transpose: WT[l][k][c] = W[l][c][k] ----------------
__global__ __launch_bounds__(128) void transpose_w_kernel(
    const float* __restrict__ W, float* __restrict__ WT)
{
    const int b = blockIdx.x;          // layer*128 + k
    const int layer = b >> 7;
    const int k = b & 127;
    const int c = threadIdx.x;
    WT[((size_t)layer << 14) + (k << 7) + c] = W[((size_t)layer << 14) + (c << 7) + k];
}

// ---------------- x0 = concat(row_embed, col_embed) -> fp16 ----------------
__global__ __launch_bounds__(256) void convert_x0_kernel(
    const float* __restrict__ xa, const float* __restrict__ xb,
    __half* __restrict__ xh, int nrows_a, int N)
{
    const int i = blockIdx.x * 256 + threadIdx.x;   // float4 group index
    if (i >= N * (DIM / 4)) return;
    const int row = i >> 5;
    const int g = i & 31;
    const float* sp = (row < nrows_a) ? xa + (size_t)row * DIM
                                      : xb + (size_t)(row - nrows_a) * DIM;
    const float4 v = ((const float4*)sp)[g];
    __half2 h0 = __floats2half2_rn(v.x, v.y);
    __half2 h1 = __floats2half2_rn(v.z, v.w);
    __half2* dp = (__half2*)(xh + (size_t)row * DIM + g * 4);
    dp[0] = h0;
    dp[1] = h1;
}

// ---------------- CSR build ----------------
__global__ __launch_bounds__(256) void zero_i_kernel(int* __restrict__ p, int n)
{
    const int i = blockIdx.x * 256 + threadIdx.x;
    if (i < n) p[i] = 0;
}

__global__ __launch_bounds__(256) void hist_kernel(
    const int* __restrict__ ei, int* __restrict__ counts, int E)
{
    const int e = blockIdx.x * 256 + threadIdx.x;
    if (e < E) atomicAdd(&counts[ei[E + e]], 1);
}

__global__ __launch_bounds__(256) void partial_sum_kernel(
    const int* __restrict__ counts, int* __restrict__ partial, int N)
{
    __shared__ int tsum[256];
    const int tid = threadIdx.x;
    const int base = blockIdx.x * 1024 + tid * 4;
    int s = 0;
    if (base + 3 < N) {
        int4 v = *(const int4*)&counts[base];
        s = v.x + v.y + v.z + v.w;
    } else {
        for (int j = 0; j < 4; ++j) if (base + j < N) s += counts[base + j];
    }
    tsum[tid] = s;
    __syncthreads();
    for (int off = 128; off; off >>= 1) {
        if (tid < off) tsum[tid] += tsum[tid + off];
        __syncthreads();
    }
    if (tid == 0) partial[blockIdx.x] = tsum[0];
}

__global__ void scan_partials_kernel(int* __restrict__ partial, int nchunks)
{
    if (threadIdx.x == 0 && blockIdx.x == 0) {
        int run = 0;
        for (int i = 0; i < nchunks; ++i) {
            int t = partial[i];
            partial[i] = run;
            run += t;
        }
    }
}

__global__ __launch_bounds__(256) void scan_chunk_kernel(
    int* __restrict__ counts, int* __restrict__ row_ptr,
    const int* __restrict__ partial, int N, int E)
{
    __shared__ int tsum[256];
    const int tid = threadIdx.x;
    const int base = blockIdx.x * 1024 + tid * 4;
    int c0 = 0, c1 = 0, c2 = 0, c3 = 0;
    if (base + 3 < N) {
        int4 v = *(const int4*)&counts[base];
        c0 = v.x; c1 = v.y; c2 = v.z; c3 = v.w;
    } else {
        if (base + 0 < N) c0 = counts[base + 0];
        if (base + 1 < N) c1 = counts[base + 1];
        if (base + 2 < N) c2 = counts[base + 2];
        if (base + 3 < N) c3 = counts[base + 3];
    }
    const int s = c0 + c1 + c2 + c3;
    tsum[tid] = s;
    __syncthreads();
    int x = s;
    for (int off = 1; off < 256; off <<= 1) {
        int y = (tid >= off) ? tsum[tid - off] : 0;
        __syncthreads();
        x += (tid >= off) ? y : 0;
        tsum[tid] = x;
        __syncthreads();
    }
    int o = partial[blockIdx.x] + x - s;
    if (base + 0 < N) { row_ptr[base + 0] = o;                counts[base + 0] = o;                }
    if (base + 1 < N) { row_ptr[base + 1] = o + c0;           counts[base + 1] = o + c0;           }
    if (base + 2 < N) { row_ptr[base + 2] = o + c0 + c1;      counts[base + 2] = o + c0 + c1;      }
    if (base + 3 < N) { row_ptr[base + 3] = o + c0 + c1 + c2; counts[base + 3] = o + c0 + c1 + c2; }
    if (tid == 0 && blockIdx.x == 0) row_ptr[N] = E;
}

__global__ __launch_bounds__(256) void csr_scatter_kernel(
    const int* __restrict__ ei, const float* __restrict__ ew,
    int* __restrict__ cursor, int2* __restrict__ rec, int E)
{
    const int e = blockIdx.x * 256 + threadIdx.x;
    if (e < E) {
        const int dst = ei[E + e];
        const int pos = atomicAdd(&cursor[dst], 1);
        rec[pos] = make_int2(ei[e], __float_as_int(ew[e]));
    }
}

// ---------------- aggregate x (fp16 gather): one wave per dst ----------------
// aggx[dst] = sum_e w_e * x[src_e];  swv[dst] = sum_e w_e
__global__ __launch_bounds__(256) void csr_agg_x_kernel(
    const int* __restrict__ row_ptr, const int2* __restrict__ rec,
    const __half* __restrict__ xh, float* __restrict__ aggx,
    float* __restrict__ swv, int N)
{
    const int dst = blockIdx.x * 4 + (threadIdx.x >> 6);
    if (dst >= N) return;
    const int lane = threadIdx.x & 63;
    const int beg = row_ptr[dst];
    const int end = row_ptr[dst + 1];
    float2 acc = make_float2(0.f, 0.f);
    float sw = 0.f;
    int p = beg;
    for (; p + 3 < end; p += 4) {
        const int2 r0 = rec[p], r1 = rec[p + 1], r2 = rec[p + 2], r3 = rec[p + 3];
        const __half2 v0 = ((const __half2*)(xh + (size_t)r0.x * DIM))[lane];
        const __half2 v1 = ((const __half2*)(xh + (size_t)r1.x * DIM))[lane];
        const __half2 v2 = ((const __half2*)(xh + (size_t)r2.x * DIM))[lane];
        const __half2 v3 = ((const __half2*)(xh + (size_t)r3.x * DIM))[lane];
        const float w0 = __int_as_float(r0.y), w1 = __int_as_float(r1.y);
        const float w2 = __int_as_float(r2.y), w3 = __int_as_float(r3.y);
        sw += w0 + w1 + w2 + w3;
        float2 f;
        f = __half22float2(v0); acc.x = fmaf(w0, f.x, acc.x); acc.y = fmaf(w0, f.y, acc.y);
        f = __half22float2(v1); acc.x = fmaf(w1, f.x, acc.x); acc.y = fmaf(w1, f.y, acc.y);
        f = __half22float2(v2); acc.x = fmaf(w2, f.x, acc.x); acc.y = fmaf(w2, f.y, acc.y);
        f = __half22float2(v3); acc.x = fmaf(w3, f.x, acc.x); acc.y = fmaf(w3, f.y, acc.y);
    }
    for (; p < end; ++p) {
        const int2 r0 = rec[p];
        const __half2 v0 = ((const __half2*)(xh + (size_t)r0.x * DIM))[lane];
        const float w0 = __int_as_float(r0.y);
        sw += w0;
        const float2 f = __half22float2(v0);
        acc.x = fmaf(w0, f.x, acc.x);
        acc.y = fmaf(w0, f.y, acc.y);
    }
    ((float2*)(aggx + (size_t)dst * DIM))[lane] = acc;
    if (lane == 0) swv[dst] = sw;
}

// ---------------- GEMM + scaled bias + relu ----------------
// out[r][c] = relu( sum_k aggx[r][k]*W[c][k] + swv[r]*b[c] )
// mode 0: write fp16 to xh_out; mode 1: write fp32 to f_out (may alias aggx)
__global__ __launch_bounds__(256) void gemm_bias_relu_kernel(
    const float* __restrict__ aggx, const float* __restrict__ WT,
    const float* __restrict__ bias, const float* __restrict__ swv,
    __half* __restrict__ xh_out, float* __restrict__ f_out, int mode, int N)
{
    __shared__ float WTs[DIM * DIM];       // WTs[k*128+c]
    __shared__ float Xs[TILE_ROWS * DIM];  // Xs[r*128+k]
    const int tid = threadIdx.x;

    for (int i = tid; i < DIM * DIM / 4; i += 256)
        ((float4*)WTs)[i] = ((const float4*)WT)[i];

    const int rbase = blockIdx.x * TILE_ROWS;
    for (int i = tid; i < TILE_ROWS * DIM / 4; i += 256) {
        int grow = rbase + (i >> 5);
        if (grow >= N) grow = N - 1;
        ((float4*)Xs)[i] = ((const float4*)(aggx + (size_t)grow * DIM))[i & 31];
    }
    __syncthreads();

    const int c0 = (tid & 31) * 4;
    const int rset = tid >> 5;
    const float4 bv = ((const float4*)bias)[tid & 31];
    float4 acc[4];
    #pragma unroll
    for (int m = 0; m < 4; ++m) {
        int grow = rbase + rset + 8 * m;
        const float sw = (grow < N) ? swv[grow] : 0.f;
        acc[m] = make_float4(sw * bv.x, sw * bv.y, sw * bv.z, sw * bv.w);
    }

    for (int k = 0; k < DIM; k += 4) {
        const float4 w0 = *(const float4*)&WTs[(k + 0) * DIM + c0];
        const float4 w1 = *(const float4*)&WTs[(k + 1) * DIM + c0];
        const float4 w2 = *(const float4*)&WTs[(k + 2) * DIM + c0];
        const float4 w3 = *(const float4*)&WTs[(k + 3) * DIM + c0];
        #pragma unroll
        for (int m = 0; m < 4; ++m) {
            const float4 xv = *(const float4*)&Xs[(rset + 8 * m) * DIM + k];
            acc[m].x = fmaf(xv.w, w3.x, fmaf(xv.z, w2.x, fmaf(xv.y, w1.x, fmaf(xv.x, w0.x, acc[m].x))));
            acc[m].y = fmaf(xv.w, w3.y, fmaf(xv.z, w2.y, fmaf(xv.y, w1.y, fmaf(xv.x, w0.y, acc[m].y))));
            acc[m].z = fmaf(xv.w, w3.z, fmaf(xv.z, w2.z, fmaf(xv.y, w1.z, fmaf(xv.x, w0.z, acc[m].z))));
            acc[m].w = fmaf(xv.w, w3.w, fmaf(xv.z, w2.w, fmaf(xv.y, w1.w, fmaf(xv.x, w0.w, acc[m].w))));
        }
    }

    #pragma unroll
    for (int m = 0; m < 4; ++m) {
        const int grow = rbase + rset + 8 * m;
        if (grow >= N) continue;
        float4 v = acc[m];
        v.x = fmaxf(v.x, 0.f); v.y = fmaxf(v.y, 0.f);
        v.z = fmaxf(v.z, 0.f); v.w = fmaxf(v.w, 0.f);
        if (mode == 0) {
            __half2* dp = (__half2*)(xh_out + (size_t)grow * DIM + c0);
            dp[0] = __floats2half2_rn(v.x, v.y);
            dp[1] = __floats2half2_rn(v.z, v.w);
        } else {
            ((float4*)(f_out + (size_t)grow * DIM))[tid & 31] = v;
        }
    }
}

extern "C" void kernel_launch(void* const* d_in, const int* in_sizes, int n_in,
                              void* d_out, int out_size, void* d_ws, size_t ws_size,
                              hipStream_t stream)
{
    const int*   ei        = (const int*)d_in[0];    // [2][E]
    const float* ew        = (const float*)d_in[1];  // [E]
    const float* row_embed = (const float*)d_in[2];  // [nrows][128]
    const float* col_embed = (const float*)d_in[3];  // [ncols][128]
    const float* W         = (const float*)d_in[4];  // [L][128][128]
    const float* bias      = (const float*)d_in[5];  // [L][128]

    const int E     = in_sizes[1];
    const int nrows = in_sizes[2] / DIM;
    const int ncols = in_sizes[3] / DIM;
    const int N     = nrows + ncols;
    const int L     = in_sizes[5] / DIM;

    // workspace layout (16B aligned slabs)
    size_t off = 0;
    auto alloc = [&](size_t bytes) -> char* {
        char* p = (char*)d_ws + off;
        off = (off + bytes + 15) & ~(size_t)15;
        return p;
    };
    float*  WT      = (float*) alloc((size_t)L * DIM * DIM * sizeof(float));
    __half* xh      = (__half*)alloc((size_t)N * DIM * sizeof(__half));
    float*  swv     = (float*) alloc((size_t)N * sizeof(float));
    int*    row_ptr = (int*)   alloc((size_t)(N + 1) * sizeof(int));
    int*    counts  = (int*)   alloc((size_t)N * sizeof(int));       // becomes cursor
    int*    partial = (int*)   alloc(1024 * sizeof(int));
    int2*   rec     = (int2*)  alloc((size_t)E * sizeof(int2));

    float* aggx = (float*)d_out;   // [N][128] — aggregation target & final output

    transpose_w_kernel<<<L * DIM, DIM, 0, stream>>>(W, WT);
    convert_x0_kernel<<<(N * (DIM / 4) + 255) / 256, 256, 0, stream>>>(
        row_embed, col_embed, xh, nrows, N);

    // CSR build
    const int nchunks = (N + 1023) / 1024;
    const int edge_blocks256 = (E + 255) / 256;
    zero_i_kernel<<<(N + 255) / 256, 256, 0, stream>>>(counts, N);
    hist_kernel<<<edge_blocks256, 256, 0, stream>>>(ei, counts, E);
    partial_sum_kernel<<<nchunks, 256, 0, stream>>>(counts, partial, N);
    scan_partials_kernel<<<1, 64, 0, stream>>>(partial, nchunks);
    scan_chunk_kernel<<<nchunks, 256, 0, stream>>>(counts, row_ptr, partial, N, E);
    csr_scatter_kernel<<<edge_blocks256, 256, 0, stream>>>(ei, ew, counts, rec, E);

    const int agg_blocks  = (N + 3) / 4;
    const int gemm_blocks = (N + TILE_ROWS - 1) / TILE_ROWS;

    for (int l = 0; l < L; ++l) {
        csr_agg_x_kernel<<<agg_blocks, 256, 0, stream>>>(row_ptr, rec, xh, aggx, swv, N);
        const int last = (l == L - 1);
        gemm_bias_relu_kernel<<<gemm_blocks, 256, 0, stream>>>(
            aggx, WT + (size_t)l * DIM * DIM, bias + (size_t)l * DIM, swv,
            xh, aggx, last ? 1 : 0, N);
    }
}

// Round 5
// 514.398 us; speedup vs baseline: 8.0492x; 1.2117x over previous
//
#include <hip/hip_runtime.h>
#include <hip/hip_fp16.h>

#define DIM 128

typedef _Float16 f16x8 __attribute__((ext_vector_type(8)));
typedef float f32x4 __attribute__((ext_vector_type(4)));

// ---------------- pack W into MFMA A-fragments ----------------
// frag index b = (l*4 + s)*8 + mt ; lane ; j
// Wf[b][lane][j] = W[l][ mt*16 + (lane&15) ][ s*32 + (lane>>4)*8 + j ]
__global__ __launch_bounds__(64) void pack_wf_kernel(
    const float* __restrict__ W, __half* __restrict__ Wf)
{
    const int b = blockIdx.x;
    const int mt = b & 7;
    const int s  = (b >> 3) & 3;
    const int l  = b >> 5;
    const int lane = threadIdx.x;
    const int c  = mt * 16 + (lane & 15);
    const int k0 = s * 32 + (lane >> 4) * 8;
    const float* wr = W + ((size_t)l << 14) + c * DIM + k0;
    __half* dp = Wf + ((size_t)b * 64 + lane) * 8;
    #pragma unroll
    for (int j = 0; j < 8; ++j) dp[j] = __float2half(wr[j]);
}

// ---------------- x0 = concat(row_embed, col_embed) -> fp16 ----------------
__global__ __launch_bounds__(256) void convert_x0_kernel(
    const float* __restrict__ xa, const float* __restrict__ xb,
    __half* __restrict__ xh, int nrows_a, int N)
{
    const int i = blockIdx.x * 256 + threadIdx.x;   // float4 group index
    if (i >= N * (DIM / 4)) return;
    const int row = i >> 5;
    const int g = i & 31;
    const float* sp = (row < nrows_a) ? xa + (size_t)row * DIM
                                      : xb + (size_t)(row - nrows_a) * DIM;
    const float4 v = ((const float4*)sp)[g];
    __half2* dp = (__half2*)(xh + (size_t)row * DIM + g * 4);
    dp[0] = __floats2half2_rn(v.x, v.y);
    dp[1] = __floats2half2_rn(v.z, v.w);
}

// ---------------- CSR build (cursor array only; end-offsets after scatter) ----
__global__ __launch_bounds__(256) void zero_i_kernel(int* __restrict__ p, int n)
{
    const int i = blockIdx.x * 256 + threadIdx.x;
    if (i < n) p[i] = 0;
}

__global__ __launch_bounds__(256) void hist_kernel(
    const int* __restrict__ ei, int* __restrict__ counts, int E)
{
    const int e = blockIdx.x * 256 + threadIdx.x;
    if (e < E) atomicAdd(&counts[ei[E + e]], 1);
}

__global__ __launch_bounds__(256) void partial_sum_kernel(
    const int* __restrict__ counts, int* __restrict__ partial, int N)
{
    __shared__ int tsum[256];
    const int tid = threadIdx.x;
    const int base = blockIdx.x * 1024 + tid * 4;
    int s = 0;
    if (base + 3 < N) {
        int4 v = *(const int4*)&counts[base];
        s = v.x + v.y + v.z + v.w;
    } else {
        for (int j = 0; j < 4; ++j) if (base + j < N) s += counts[base + j];
    }
    tsum[tid] = s;
    __syncthreads();
    for (int off = 128; off; off >>= 1) {
        if (tid < off) tsum[tid] += tsum[tid + off];
        __syncthreads();
    }
    if (tid == 0) partial[blockIdx.x] = tsum[0];
}

__global__ void scan_partials_kernel(int* __restrict__ partial, int nchunks)
{
    if (threadIdx.x == 0 && blockIdx.x == 0) {
        int run = 0;
        for (int i = 0; i < nchunks; ++i) {
            int t = partial[i];
            partial[i] = run;
            run += t;
        }
    }
}

// in-place: counts -> exclusive prefix (cursor start offsets)
__global__ __launch_bounds__(256) void scan_chunk_kernel(
    int* __restrict__ counts, const int* __restrict__ partial, int N)
{
    __shared__ int tsum[256];
    const int tid = threadIdx.x;
    const int base = blockIdx.x * 1024 + tid * 4;
    int c0 = 0, c1 = 0, c2 = 0, c3 = 0;
    if (base + 3 < N) {
        int4 v = *(const int4*)&counts[base];
        c0 = v.x; c1 = v.y; c2 = v.z; c3 = v.w;
    } else {
        if (base + 0 < N) c0 = counts[base + 0];
        if (base + 1 < N) c1 = counts[base + 1];
        if (base + 2 < N) c2 = counts[base + 2];
        if (base + 3 < N) c3 = counts[base + 3];
    }
    const int s = c0 + c1 + c2 + c3;
    tsum[tid] = s;
    __syncthreads();
    int x = s;
    for (int off = 1; off < 256; off <<= 1) {
        int y = (tid >= off) ? tsum[tid - off] : 0;
        __syncthreads();
        x += (tid >= off) ? y : 0;
        tsum[tid] = x;
        __syncthreads();
    }
    const int o = partial[blockIdx.x] + x - s;
    if (base + 0 < N) counts[base + 0] = o;
    if (base + 1 < N) counts[base + 1] = o + c0;
    if (base + 2 < N) counts[base + 2] = o + c0 + c1;
    if (base + 3 < N) counts[base + 3] = o + c0 + c1 + c2;
}

__global__ __launch_bounds__(256) void csr_scatter_kernel(
    const int* __restrict__ ei, const float* __restrict__ ew,
    int* __restrict__ cursor, int2* __restrict__ rec, int E)
{
    const int e = blockIdx.x * 256 + threadIdx.x;
    if (e < E) {
        const int dst = ei[E + e];
        const int pos = atomicAdd(&cursor[dst], 1);
        rec[pos] = make_int2(ei[e], __float_as_int(ew[e]));
    }
}

// ---------------- aggregate x (fp16 gather, fp16 out): one wave per dst -------
// after csr_scatter: cursor[d] = end offset of segment d; beg = cursor[d-1]
__global__ __launch_bounds__(256) void csr_agg_x_kernel(
    const int* __restrict__ cursor, const int2* __restrict__ rec,
    const __half* __restrict__ xh, __half* __restrict__ aggx,
    float* __restrict__ swv, int N)
{
    const int dst = blockIdx.x * 4 + (threadIdx.x >> 6);
    if (dst >= N) return;
    const int lane = threadIdx.x & 63;
    const int end = cursor[dst];
    const int beg = (dst == 0) ? 0 : cursor[dst - 1];
    float2 acc = make_float2(0.f, 0.f);
    float sw = 0.f;
    int p = beg;
    for (; p + 3 < end; p += 4) {
        const int2 r0 = rec[p], r1 = rec[p + 1], r2 = rec[p + 2], r3 = rec[p + 3];
        const __half2 v0 = ((const __half2*)(xh + (size_t)r0.x * DIM))[lane];
        const __half2 v1 = ((const __half2*)(xh + (size_t)r1.x * DIM))[lane];
        const __half2 v2 = ((const __half2*)(xh + (size_t)r2.x * DIM))[lane];
        const __half2 v3 = ((const __half2*)(xh + (size_t)r3.x * DIM))[lane];
        const float w0 = __int_as_float(r0.y), w1 = __int_as_float(r1.y);
        const float w2 = __int_as_float(r2.y), w3 = __int_as_float(r3.y);
        sw += w0 + w1 + w2 + w3;
        float2 f;
        f = __half22float2(v0); acc.x = fmaf(w0, f.x, acc.x); acc.y = fmaf(w0, f.y, acc.y);
        f = __half22float2(v1); acc.x = fmaf(w1, f.x, acc.x); acc.y = fmaf(w1, f.y, acc.y);
        f = __half22float2(v2); acc.x = fmaf(w2, f.x, acc.x); acc.y = fmaf(w2, f.y, acc.y);
        f = __half22float2(v3); acc.x = fmaf(w3, f.x, acc.x); acc.y = fmaf(w3, f.y, acc.y);
    }
    for (; p < end; ++p) {
        const int2 r0 = rec[p];
        const __half2 v0 = ((const __half2*)(xh + (size_t)r0.x * DIM))[lane];
        const float w0 = __int_as_float(r0.y);
        sw += w0;
        const float2 f = __half22float2(v0);
        acc.x = fmaf(w0, f.x, acc.x);
        acc.y = fmaf(w0, f.y, acc.y);
    }
    ((__half2*)(aggx + (size_t)dst * DIM))[lane] = __floats2half2_rn(acc.x, acc.y);
    if (lane == 0) swv[dst] = sw;
}

// ---------------- MFMA GEMM: D = W · X^T  (channels x nodes) ----------------
// out[node][ch] = relu( sum_k X[node][k]*W[ch][k] + swv[node]*b[ch] )
// mode 0: fp16 out_h ; mode 1: fp32 out_f
__global__ __launch_bounds__(256) void gemm_mfma_kernel(
    const __half* __restrict__ X, const __half* __restrict__ Wf,
    const float* __restrict__ bias, const float* __restrict__ swv,
    __half* __restrict__ out_h, float* __restrict__ out_f, int mode, int N)
{
    const int wave = threadIdx.x >> 6;
    const int lane = threadIdx.x & 63;
    const int g = lane >> 4;          // lane-group (k-slice)
    const int e = lane & 15;          // node-within-tile (B n) / channel (A m)
    const int nbase = blockIdx.x * 128 + wave * 32;   // two 16-node tiles

    const int n0 = min(nbase + e, N - 1);
    const int n1 = min(nbase + 16 + e, N - 1);

    f32x4 acc[2][8];
    #pragma unroll
    for (int t = 0; t < 2; ++t)
        #pragma unroll
        for (int mt = 0; mt < 8; ++mt)
            acc[t][mt] = (f32x4){0.f, 0.f, 0.f, 0.f};

    const f16x8* Xr0 = (const f16x8*)(X + (size_t)n0 * DIM + g * 8);
    const f16x8* Xr1 = (const f16x8*)(X + (size_t)n1 * DIM + g * 8);
    const f16x8* Wp  = (const f16x8*)Wf;   // [(s*8+mt)*64 + lane]

    #pragma unroll
    for (int s = 0; s < 4; ++s) {
        const f16x8 b0 = Xr0[s * 4];       // k0 = g*8 + s*32
        const f16x8 b1 = Xr1[s * 4];
        #pragma unroll
        for (int mt = 0; mt < 8; ++mt) {
            const f16x8 a = Wp[(s * 8 + mt) * 64 + lane];
            acc[0][mt] = __builtin_amdgcn_mfma_f32_16x16x32_f16(a, b0, acc[0][mt], 0, 0, 0);
            acc[1][mt] = __builtin_amdgcn_mfma_f32_16x16x32_f16(a, b1, acc[1][mt], 0, 0, 0);
        }
    }

    // D layout: col = lane&15 -> node ; row = g*4 + reg -> channel (mt*16 + ...)
    #pragma unroll
    for (int t = 0; t < 2; ++t) {
        const int node = nbase + t * 16 + e;
        if (node >= N) continue;
        const float sw = swv[node];
        #pragma unroll
        for (int mt = 0; mt < 8; ++mt) {
            const int ch0 = mt * 16 + g * 4;
            const float4 bv = *(const float4*)(bias + ch0);
            float4 v;
            v.x = fmaxf(fmaf(sw, bv.x, acc[t][mt][0]), 0.f);
            v.y = fmaxf(fmaf(sw, bv.y, acc[t][mt][1]), 0.f);
            v.z = fmaxf(fmaf(sw, bv.z, acc[t][mt][2]), 0.f);
            v.w = fmaxf(fmaf(sw, bv.w, acc[t][mt][3]), 0.f);
            if (mode == 0) {
                const __half2 h01 = __floats2half2_rn(v.x, v.y);
                const __half2 h23 = __floats2half2_rn(v.z, v.w);
                uint2 u;
                u.x = *(const unsigned*)&h01;
                u.y = *(const unsigned*)&h23;
                *(uint2*)(out_h + (size_t)node * DIM + ch0) = u;
            } else {
                *(float4*)(out_f + (size_t)node * DIM + ch0) = v;
            }
        }
    }
}

extern "C" void kernel_launch(void* const* d_in, const int* in_sizes, int n_in,
                              void* d_out, int out_size, void* d_ws, size_t ws_size,
                              hipStream_t stream)
{
    const int*   ei        = (const int*)d_in[0];    // [2][E]
    const float* ew        = (const float*)d_in[1];  // [E]
    const float* row_embed = (const float*)d_in[2];  // [nrows][128]
    const float* col_embed = (const float*)d_in[3];  // [ncols][128]
    const float* W         = (const float*)d_in[4];  // [L][128][128]
    const float* bias      = (const float*)d_in[5];  // [L][128]

    const int E     = in_sizes[1];
    const int nrows = in_sizes[2] / DIM;
    const int ncols = in_sizes[3] / DIM;
    const int N     = nrows + ncols;
    const int L     = in_sizes[5] / DIM;

    // workspace layout (16B aligned slabs)
    size_t off = 0;
    auto alloc = [&](size_t bytes) -> char* {
        char* p = (char*)d_ws + off;
        off = (off + bytes + 15) & ~(size_t)15;
        return p;
    };
    __half* Wf      = (__half*)alloc((size_t)L * 4 * 8 * 64 * 8 * sizeof(__half));
    __half* xh      = (__half*)alloc((size_t)N * DIM * sizeof(__half));
    __half* aggx    = (__half*)alloc((size_t)N * DIM * sizeof(__half));
    float*  swv     = (float*) alloc((size_t)N * sizeof(float));
    int*    cursor  = (int*)   alloc((size_t)N * sizeof(int));
    int*    partial = (int*)   alloc(1024 * sizeof(int));
    int2*   rec     = (int2*)  alloc((size_t)E * sizeof(int2));

    pack_wf_kernel<<<L * 32, 64, 0, stream>>>(W, Wf);
    convert_x0_kernel<<<(N * (DIM / 4) + 255) / 256, 256, 0, stream>>>(
        row_embed, col_embed, xh, nrows, N);

    // CSR build
    const int nchunks = (N + 1023) / 1024;
    const int edge_blocks256 = (E + 255) / 256;
    zero_i_kernel<<<(N + 255) / 256, 256, 0, stream>>>(cursor, N);
    hist_kernel<<<edge_blocks256, 256, 0, stream>>>(ei, cursor, E);
    partial_sum_kernel<<<nchunks, 256, 0, stream>>>(cursor, partial, N);
    scan_partials_kernel<<<1, 64, 0, stream>>>(partial, nchunks);
    scan_chunk_kernel<<<nchunks, 256, 0, stream>>>(cursor, partial, N);
    csr_scatter_kernel<<<edge_blocks256, 256, 0, stream>>>(ei, ew, cursor, rec, E);

    const int agg_blocks  = (N + 3) / 4;
    const int gemm_blocks = (N + 127) / 128;

    for (int l = 0; l < L; ++l) {
        csr_agg_x_kernel<<<agg_blocks, 256, 0, stream>>>(cursor, rec, xh, aggx, swv, N);
        const int last = (l == L - 1);
        gemm_mfma_kernel<<<gemm_blocks, 256, 0, stream>>>(
            aggx, Wf + (size_t)l * 16384, bias + (size_t)l * DIM, swv,
            xh, (float*)d_out, last ? 1 : 0, N);
    }
}